// Round 1
// baseline (10824.420 us; speedup 1.0000x reference)
//
#include <hip/hip_runtime.h>
#include <cstddef>

#define HD 256      // hidden channels
#define CD 16       // data channels
#define BLOCK 512   // 8 waves; thread = (e = t>>6 in 0..7, cg = t&63 -> 4 output cols)

// LDS: half of prop-layer0 (rows e*32+0..15 per wave-slice), in_weight, biases, scratch.
// Total = 131072 + 16384 + 8192 + 1024 + 2048 + 3072 + 64 + 64 = 161920 B <= 163840 B.
struct alignas(16) SMem {
  float w0[128 * HD];     // lds row (e*16+i) <- global row (e*32+i), i<16
  float win[CD * HD];     // in_weight[b] : [c][k]
  float part[8][HD];
  float h[HD];
  float outp[BLOCK];
  float bin[HD];
  float b0[HD];
  float b1[HD];
  float y[CD];
  float bout[CD];
};

__global__ __launch_bounds__(BLOCK, 2)
void decoder_persistent(const float* __restrict__ y0,
                        const float* __restrict__ in_w,
                        const float* __restrict__ in_b,
                        const float* __restrict__ out_w,
                        const float* __restrict__ out_b,
                        const float* __restrict__ prop_w,
                        const float* __restrict__ prop_b,
                        const float* __restrict__ cutoff,
                        const int*   __restrict__ plen,
                        float* __restrict__ out)
{
  __shared__ SMem sm;
  const int b  = blockIdx.x;
  const int t  = threadIdx.x;
  const int e  = t >> 6;     // wave id: owns hidden rows e*32..e*32+31 (as reduction slice)
  const int cg = t & 63;     // owns output cols cg*4..cg*4+3
  const int T  = plen[0];
  const float ct = cutoff[0];
  const float dtc = 1e-6f;

  const float* W0g = prop_w + (size_t)b * 2u * HD * HD;
  const float* W1g = W0g + HD * HD;
  const float* Wig = in_w  + (size_t)b * CD * HD;
  const float* Wog = out_w + (size_t)b * HD * CD;

  // ---------------- one-time LDS fill (coalesced float4) ----------------
  for (int idx = t; idx < 128 * HD / 4; idx += BLOCK) {
    const int L  = idx >> 6;                    // lds row 0..127
    const int q  = idx & 63;                    // col group
    const int gr = ((L >> 4) * 32) + (L & 15);  // global row
    *(float4*)(sm.w0 + L * HD + q * 4) =
        *(const float4*)(W0g + (size_t)gr * HD + q * 4);
  }
  for (int idx = t; idx < CD * HD / 4; idx += BLOCK) {
    *(float4*)(sm.win + idx * 4) = *(const float4*)(Wig + idx * 4);
  }
  if (t < HD) {
    sm.bin[t] = in_b[(size_t)b * HD + t];
    sm.b0[t]  = prop_b[((size_t)b * 2) * HD + t];
    sm.b1[t]  = prop_b[((size_t)b * 2 + 1) * HD + t];
  }
  if (t < CD) {
    sm.bout[t] = out_b[(size_t)b * CD + t];
    sm.y[t]    = y0[(size_t)b * CD + t];
  }

  // ---------------- one-time register weight caches ----------------
  // prop0 rows e*32+16 .. e*32+31 (the half not in LDS), cols cg*4..+3
  float w0r[16][4];
#pragma unroll
  for (int j = 0; j < 16; ++j) {
    const float4 v = *(const float4*)(W0g + (size_t)(e * 32 + 16 + j) * HD + cg * 4);
    w0r[j][0] = v.x; w0r[j][1] = v.y; w0r[j][2] = v.z; w0r[j][3] = v.w;
  }
  // prop1 rows e*32 .. e*32+31, cols cg*4..+3  (fully in registers)
  float w1r[32][4];
#pragma unroll
  for (int j = 0; j < 32; ++j) {
    const float4 v = *(const float4*)(W1g + (size_t)(e * 32 + j) * HD + cg * 4);
    w1r[j][0] = v.x; w1r[j][1] = v.y; w1r[j][2] = v.z; w1r[j][3] = v.w;
  }
  // out layer: thread t handles channel oc = t&15, rows og*8..og*8+7
  const int oc = t & 15;
  const int og = t >> 4;
  float wor[8];
#pragma unroll
  for (int j = 0; j < 8; ++j) wor[j] = Wog[(size_t)(og * 8 + j) * CD + oc];

  __syncthreads();

  float* outb = out + (size_t)b * CD * T;
  const int rbase = e * 32;   // this wave's reduction-row base
  const int lb    = e * 16;   // lds row base for first 16 of those rows

  for (int step = 0; step < T; ++step) {
    // ---- P1: input layer partials: part[e][k] = sum_{c in 2e,2e+1} y[c]*Win[c][k]
    {
      const float ya = sm.y[e * 2 + 0];
      const float yb = sm.y[e * 2 + 1];
      const float4 wA = *(const float4*)(sm.win + (e * 2 + 0) * HD + cg * 4);
      const float4 wB = *(const float4*)(sm.win + (e * 2 + 1) * HD + cg * 4);
      float4 a;
      a.x = ya * wA.x + yb * wB.x;
      a.y = ya * wA.y + yb * wB.y;
      a.z = ya * wA.z + yb * wB.z;
      a.w = ya * wA.w + yb * wB.w;
      *(float4*)(&sm.part[e][cg * 4]) = a;
    }
    __syncthreads();
    // ---- P2: combine -> h
    if (t < HD) {
      float s = sm.bin[t];
#pragma unroll
      for (int q = 0; q < 8; ++q) s += sm.part[q][t];
      sm.h[t] = fmaxf(s, 0.0f);
    }
    __syncthreads();
    // ---- P3: prop layer 0 partials: 16 LDS rows + 16 register rows
    {
      float ax = 0.f, ay = 0.f, az = 0.f, aw = 0.f;
#pragma unroll
      for (int rc = 0; rc < 4; ++rc) {
        const float4 hv = *(const float4*)(sm.h + rbase + rc * 4);
        const float4 wa = *(const float4*)(sm.w0 + (lb + rc * 4 + 0) * HD + cg * 4);
        const float4 wb = *(const float4*)(sm.w0 + (lb + rc * 4 + 1) * HD + cg * 4);
        const float4 wc = *(const float4*)(sm.w0 + (lb + rc * 4 + 2) * HD + cg * 4);
        const float4 wd = *(const float4*)(sm.w0 + (lb + rc * 4 + 3) * HD + cg * 4);
        ax += hv.x * wa.x + hv.y * wb.x + hv.z * wc.x + hv.w * wd.x;
        ay += hv.x * wa.y + hv.y * wb.y + hv.z * wc.y + hv.w * wd.y;
        az += hv.x * wa.z + hv.y * wb.z + hv.z * wc.z + hv.w * wd.z;
        aw += hv.x * wa.w + hv.y * wb.w + hv.z * wc.w + hv.w * wd.w;
      }
#pragma unroll
      for (int rc = 0; rc < 4; ++rc) {
        const float4 hv = *(const float4*)(sm.h + rbase + 16 + rc * 4);
        ax += hv.x*w0r[rc*4+0][0] + hv.y*w0r[rc*4+1][0] + hv.z*w0r[rc*4+2][0] + hv.w*w0r[rc*4+3][0];
        ay += hv.x*w0r[rc*4+0][1] + hv.y*w0r[rc*4+1][1] + hv.z*w0r[rc*4+2][1] + hv.w*w0r[rc*4+3][1];
        az += hv.x*w0r[rc*4+0][2] + hv.y*w0r[rc*4+1][2] + hv.z*w0r[rc*4+2][2] + hv.w*w0r[rc*4+3][2];
        aw += hv.x*w0r[rc*4+0][3] + hv.y*w0r[rc*4+1][3] + hv.z*w0r[rc*4+2][3] + hv.w*w0r[rc*4+3][3];
      }
      float4 a; a.x = ax; a.y = ay; a.z = az; a.w = aw;
      *(float4*)(&sm.part[e][cg * 4]) = a;
    }
    __syncthreads();
    // ---- P4: combine -> h
    if (t < HD) {
      float s = sm.b0[t];
#pragma unroll
      for (int q = 0; q < 8; ++q) s += sm.part[q][t];
      sm.h[t] = fmaxf(s, 0.0f);
    }
    __syncthreads();
    // ---- P5: prop layer 1 partials: all register rows
    {
      float ax = 0.f, ay = 0.f, az = 0.f, aw = 0.f;
#pragma unroll
      for (int rc = 0; rc < 8; ++rc) {
        const float4 hv = *(const float4*)(sm.h + rbase + rc * 4);
        ax += hv.x*w1r[rc*4+0][0] + hv.y*w1r[rc*4+1][0] + hv.z*w1r[rc*4+2][0] + hv.w*w1r[rc*4+3][0];
        ay += hv.x*w1r[rc*4+0][1] + hv.y*w1r[rc*4+1][1] + hv.z*w1r[rc*4+2][1] + hv.w*w1r[rc*4+3][1];
        az += hv.x*w1r[rc*4+0][2] + hv.y*w1r[rc*4+1][2] + hv.z*w1r[rc*4+2][2] + hv.w*w1r[rc*4+3][2];
        aw += hv.x*w1r[rc*4+0][3] + hv.y*w1r[rc*4+1][3] + hv.z*w1r[rc*4+2][3] + hv.w*w1r[rc*4+3][3];
      }
      float4 a; a.x = ax; a.y = ay; a.z = az; a.w = aw;
      *(float4*)(&sm.part[e][cg * 4]) = a;
    }
    __syncthreads();
    // ---- P6: combine -> h
    if (t < HD) {
      float s = sm.b1[t];
#pragma unroll
      for (int q = 0; q < 8; ++q) s += sm.part[q][t];
      sm.h[t] = fmaxf(s, 0.0f);
    }
    __syncthreads();
    // ---- P7: output layer partials (registers): outp[t] = sum_{j} h[og*8+j]*Wout[og*8+j][oc]
    {
      float acc = 0.f;
#pragma unroll
      for (int j = 0; j < 8; ++j) acc += sm.h[og * 8 + j] * wor[j];
      sm.outp[t] = acc;
    }
    __syncthreads();
    // ---- P8: reduce 32 partials/channel, tanh update, store
    if (t < CD) {
      float s = sm.bout[t];
#pragma unroll
      for (int g = 0; g < 32; ++g) s += sm.outp[t + g * 16];
      const float yv = sm.y[t] + ct * tanhf(dtc * s / ct);
      sm.y[t] = yv;
      outb[(size_t)t * T + step] = yv;
    }
    __syncthreads();
  }
}

extern "C" void kernel_launch(void* const* d_in, const int* in_sizes, int n_in,
                              void* d_out, int out_size, void* d_ws, size_t ws_size,
                              hipStream_t stream) {
  (void)in_sizes; (void)n_in; (void)out_size; (void)d_ws; (void)ws_size;
  const float* y0     = (const float*)d_in[0];
  const float* in_w   = (const float*)d_in[1];
  const float* in_b   = (const float*)d_in[2];
  const float* out_w  = (const float*)d_in[3];
  const float* out_b  = (const float*)d_in[4];
  const float* prop_w = (const float*)d_in[5];
  const float* prop_b = (const float*)d_in[6];
  const float* cutoff = (const float*)d_in[7];
  const int*   plen   = (const int*)d_in[8];
  float* out = (float*)d_out;

  decoder_persistent<<<256, BLOCK, 0, stream>>>(
      y0, in_w, in_b, out_w, out_b, prop_w, prop_b, cutoff, plen, out);
}

// Round 2
// 3894.757 us; speedup vs baseline: 2.7792x; 2.7792x over previous
//
#include <hip/hip_runtime.h>
#include <cstddef>

#define HD 256      // hidden channels
#define CD 16       // data channels
#define BLOCK 256   // 4 waves; thread = (e = t>>6 in 0..3, cg = t&63 -> 4 output cols)

// LDS total = 131072 + 16384 + 4096 + 1024 + 1024 + 3072 + 64 + 64 = 156800 B < 163840 B.
struct alignas(16) SMem {
  float w0[128 * HD];     // lds row (e*32+i) <- global row (e*64+i), i<32, e<4
  float win[CD * HD];     // in_weight[b] : [c][k]
  float part[4][HD];      // per-wave partial sums
  float h[HD];
  float outp[BLOCK];
  float bin[HD];
  float b0[HD];
  float b1[HD];
  float y[CD];
  float bout[CD];
};

__global__ __launch_bounds__(BLOCK, 1)
void decoder_persistent(const float* __restrict__ y0,
                        const float* __restrict__ in_w,
                        const float* __restrict__ in_b,
                        const float* __restrict__ out_w,
                        const float* __restrict__ out_b,
                        const float* __restrict__ prop_w,
                        const float* __restrict__ prop_b,
                        const float* __restrict__ cutoff,
                        const int*   __restrict__ plen,
                        float* __restrict__ out)
{
  __shared__ SMem sm;
  const int b  = blockIdx.x;
  const int t  = threadIdx.x;
  const int e  = t >> 6;     // wave id: owns hidden rows e*64..e*64+63 (reduction slice)
  const int cg = t & 63;     // owns output cols cg*4..cg*4+3
  const int T  = plen[0];
  const float ct = cutoff[0];
  const float dtc = 1e-6f;

  const float* W0g = prop_w + (size_t)b * 2u * HD * HD;
  const float* W1g = W0g + HD * HD;
  const float* Wig = in_w  + (size_t)b * CD * HD;
  const float* Wog = out_w + (size_t)b * HD * CD;

  // ---------------- one-time LDS fill (coalesced float4) ----------------
  for (int idx = t; idx < 128 * HD / 4; idx += BLOCK) {
    const int L  = idx >> 6;                    // lds row 0..127
    const int q  = idx & 63;                    // col group
    const int gr = ((L >> 5) * 64) + (L & 31);  // global row
    *(float4*)(sm.w0 + L * HD + q * 4) =
        *(const float4*)(W0g + (size_t)gr * HD + q * 4);
  }
  for (int idx = t; idx < CD * HD / 4; idx += BLOCK) {
    *(float4*)(sm.win + idx * 4) = *(const float4*)(Wig + idx * 4);
  }
  // all 256 threads: one bias element each
  sm.bin[t] = in_b[(size_t)b * HD + t];
  sm.b0[t]  = prop_b[((size_t)b * 2) * HD + t];
  sm.b1[t]  = prop_b[((size_t)b * 2 + 1) * HD + t];
  if (t < CD) {
    sm.bout[t] = out_b[(size_t)b * CD + t];
    sm.y[t]    = y0[(size_t)b * CD + t];
  }

  // ---------------- one-time register weight caches ----------------
  // prop0 rows e*64+32 .. e*64+63 (half not in LDS), cols cg*4..+3
  float w0r[32][4];
#pragma unroll
  for (int j = 0; j < 32; ++j) {
    const float4 v = *(const float4*)(W0g + (size_t)(e * 64 + 32 + j) * HD + cg * 4);
    w0r[j][0] = v.x; w0r[j][1] = v.y; w0r[j][2] = v.z; w0r[j][3] = v.w;
  }
  // prop1 rows e*64 .. e*64+63, cols cg*4..+3 (fully in registers)
  float w1r[64][4];
#pragma unroll
  for (int j = 0; j < 64; ++j) {
    const float4 v = *(const float4*)(W1g + (size_t)(e * 64 + j) * HD + cg * 4);
    w1r[j][0] = v.x; w1r[j][1] = v.y; w1r[j][2] = v.z; w1r[j][3] = v.w;
  }
  // out layer: thread t handles channel oc = t&15, rows og*16..og*16+15
  const int oc = t & 15;
  const int og = t >> 4;
  float wor[16];
#pragma unroll
  for (int j = 0; j < 16; ++j) wor[j] = Wog[(size_t)(og * 16 + j) * CD + oc];

  __syncthreads();

  float* outb = out + (size_t)b * CD * T;
  const int rbase = e * 64;   // this wave's reduction-row base
  const int lb    = e * 32;   // lds row base for first 32 of those rows

  for (int step = 0; step < T; ++step) {
    // ---- P1: input layer partials: part[e][k] = sum_{c in 4e..4e+3} y[c]*Win[c][k]
    {
      float ax = 0.f, ay = 0.f, az = 0.f, aw = 0.f;
#pragma unroll
      for (int c2 = 0; c2 < 4; ++c2) {
        const float yv = sm.y[e * 4 + c2];
        const float4 w = *(const float4*)(sm.win + (e * 4 + c2) * HD + cg * 4);
        ax += yv * w.x; ay += yv * w.y; az += yv * w.z; aw += yv * w.w;
      }
      float4 a; a.x = ax; a.y = ay; a.z = az; a.w = aw;
      *(float4*)(&sm.part[e][cg * 4]) = a;
    }
    __syncthreads();
    // ---- P2: combine -> h  (all 256 threads, one element each)
    {
      float s = sm.bin[t] + sm.part[0][t] + sm.part[1][t] + sm.part[2][t] + sm.part[3][t];
      sm.h[t] = fmaxf(s, 0.0f);
    }
    __syncthreads();
    // ---- P3: prop layer 0 partials: 32 LDS rows + 32 register rows
    {
      float ax = 0.f, ay = 0.f, az = 0.f, aw = 0.f;
#pragma unroll
      for (int rc = 0; rc < 8; ++rc) {
        const float4 hv = *(const float4*)(sm.h + rbase + rc * 4);
        const float4 wa = *(const float4*)(sm.w0 + (lb + rc * 4 + 0) * HD + cg * 4);
        const float4 wb = *(const float4*)(sm.w0 + (lb + rc * 4 + 1) * HD + cg * 4);
        const float4 wc = *(const float4*)(sm.w0 + (lb + rc * 4 + 2) * HD + cg * 4);
        const float4 wd = *(const float4*)(sm.w0 + (lb + rc * 4 + 3) * HD + cg * 4);
        ax += hv.x * wa.x + hv.y * wb.x + hv.z * wc.x + hv.w * wd.x;
        ay += hv.x * wa.y + hv.y * wb.y + hv.z * wc.y + hv.w * wd.y;
        az += hv.x * wa.z + hv.y * wb.z + hv.z * wc.z + hv.w * wd.z;
        aw += hv.x * wa.w + hv.y * wb.w + hv.z * wc.w + hv.w * wd.w;
      }
#pragma unroll
      for (int rc = 0; rc < 8; ++rc) {
        const float4 hv = *(const float4*)(sm.h + rbase + 32 + rc * 4);
        ax += hv.x*w0r[rc*4+0][0] + hv.y*w0r[rc*4+1][0] + hv.z*w0r[rc*4+2][0] + hv.w*w0r[rc*4+3][0];
        ay += hv.x*w0r[rc*4+0][1] + hv.y*w0r[rc*4+1][1] + hv.z*w0r[rc*4+2][1] + hv.w*w0r[rc*4+3][1];
        az += hv.x*w0r[rc*4+0][2] + hv.y*w0r[rc*4+1][2] + hv.z*w0r[rc*4+2][2] + hv.w*w0r[rc*4+3][2];
        aw += hv.x*w0r[rc*4+0][3] + hv.y*w0r[rc*4+1][3] + hv.z*w0r[rc*4+2][3] + hv.w*w0r[rc*4+3][3];
      }
      float4 a; a.x = ax; a.y = ay; a.z = az; a.w = aw;
      *(float4*)(&sm.part[e][cg * 4]) = a;
    }
    __syncthreads();
    // ---- P4: combine -> h
    {
      float s = sm.b0[t] + sm.part[0][t] + sm.part[1][t] + sm.part[2][t] + sm.part[3][t];
      sm.h[t] = fmaxf(s, 0.0f);
    }
    __syncthreads();
    // ---- P5: prop layer 1 partials: all 64 rows from registers
    {
      float ax = 0.f, ay = 0.f, az = 0.f, aw = 0.f;
#pragma unroll
      for (int rc = 0; rc < 16; ++rc) {
        const float4 hv = *(const float4*)(sm.h + rbase + rc * 4);
        ax += hv.x*w1r[rc*4+0][0] + hv.y*w1r[rc*4+1][0] + hv.z*w1r[rc*4+2][0] + hv.w*w1r[rc*4+3][0];
        ay += hv.x*w1r[rc*4+0][1] + hv.y*w1r[rc*4+1][1] + hv.z*w1r[rc*4+2][1] + hv.w*w1r[rc*4+3][1];
        az += hv.x*w1r[rc*4+0][2] + hv.y*w1r[rc*4+1][2] + hv.z*w1r[rc*4+2][2] + hv.w*w1r[rc*4+3][2];
        aw += hv.x*w1r[rc*4+0][3] + hv.y*w1r[rc*4+1][3] + hv.z*w1r[rc*4+2][3] + hv.w*w1r[rc*4+3][3];
      }
      float4 a; a.x = ax; a.y = ay; a.z = az; a.w = aw;
      *(float4*)(&sm.part[e][cg * 4]) = a;
    }
    __syncthreads();
    // ---- P6: combine -> h
    {
      float s = sm.b1[t] + sm.part[0][t] + sm.part[1][t] + sm.part[2][t] + sm.part[3][t];
      sm.h[t] = fmaxf(s, 0.0f);
    }
    __syncthreads();
    // ---- P7: output layer partials: outp[t] = sum_j h[og*16+j]*Wout[og*16+j][oc]
    {
      float acc = 0.f;
#pragma unroll
      for (int j = 0; j < 16; ++j) acc += sm.h[og * 16 + j] * wor[j];
      sm.outp[t] = acc;
    }
    __syncthreads();
    // ---- P8: reduce 16 partials/channel, tanh update, store
    if (t < CD) {
      float s = sm.bout[t];
#pragma unroll
      for (int g = 0; g < 16; ++g) s += sm.outp[t + g * 16];
      const float yv = sm.y[t] + ct * tanhf(dtc * s / ct);
      sm.y[t] = yv;
      outb[(size_t)t * T + step] = yv;
    }
    __syncthreads();
  }
}

extern "C" void kernel_launch(void* const* d_in, const int* in_sizes, int n_in,
                              void* d_out, int out_size, void* d_ws, size_t ws_size,
                              hipStream_t stream) {
  (void)in_sizes; (void)n_in; (void)out_size; (void)d_ws; (void)ws_size;
  const float* y0     = (const float*)d_in[0];
  const float* in_w   = (const float*)d_in[1];
  const float* in_b   = (const float*)d_in[2];
  const float* out_w  = (const float*)d_in[3];
  const float* out_b  = (const float*)d_in[4];
  const float* prop_w = (const float*)d_in[5];
  const float* prop_b = (const float*)d_in[6];
  const float* cutoff = (const float*)d_in[7];
  const int*   plen   = (const int*)d_in[8];
  float* out = (float*)d_out;

  decoder_persistent<<<256, BLOCK, 0, stream>>>(
      y0, in_w, in_b, out_w, out_b, prop_w, prop_b, cutoff, plen, out);
}